// Round 1
// baseline (636.283 us; speedup 1.0000x reference)
//
#include <hip/hip_runtime.h>

// Problem constants
#define B_ 128
#define T_ 256
#define F_ 1024
#define C_ 512

// GEMM tiling: 128x128 block tile, BK=16, 256 threads, 8x8 per thread
#define BM 128
#define BN 128
#define BK 16

// ---------------------------------------------------------------------------
// GEMM: I[m, n] = sum_k X[row(m), k] * W[k, n]
//   m = chunk-local row = b*CT + tt ; global X row = b*T_ + t0 + tt
//   I is the chunk buffer [B_*CT, C_]
// ---------------------------------------------------------------------------
__global__ __launch_bounds__(256) void snn_gemm_kernel(
    const float* __restrict__ X, const float* __restrict__ Wm,
    float* __restrict__ I, int t0, int CT, int lct) {
  __shared__ float As[BK][BM + 4];  // transposed: As[k][m]
  __shared__ float Bs[BK][BN + 4];

  const int tid = threadIdx.x;
  const int m0 = blockIdx.x * BM;
  const int n0 = blockIdx.y * BN;

  // A staging: 512 float4 per tile (128 rows x 4 float4). Each thread: idx, idx+256.
  const int rowA0 = tid >> 2, c4A0 = tid & 3;
  const int rowA1 = (tid + 256) >> 2, c4A1 = (tid + 256) & 3;
  const int mg0 = m0 + rowA0, mg1 = m0 + rowA1;
  const int ctm1 = CT - 1;
  const float* pA0 =
      X + (size_t)((mg0 >> lct) * T_ + t0 + (mg0 & ctm1)) * F_ + c4A0 * 4;
  const float* pA1 =
      X + (size_t)((mg1 >> lct) * T_ + t0 + (mg1 & ctm1)) * F_ + c4A1 * 4;

  // B staging: 512 float4 per tile (16 rows x 32 float4).
  const int krB0 = tid >> 5, cB0 = (tid & 31) * 4;
  const int krB1 = (tid + 256) >> 5;
  const float* pB0 = Wm + (size_t)krB0 * C_ + n0 + cB0;
  const float* pB1 = Wm + (size_t)krB1 * C_ + n0 + cB0;

  const int ty = tid >> 4;  // m-sub block (0..15) -> rows ty*8..ty*8+7
  const int tx = tid & 15;  // n-sub block (0..15) -> cols tx*8..tx*8+7

  float acc[8][8] = {};

  // prologue: load tile 0
  float4 a0 = *(const float4*)(pA0);
  float4 a1 = *(const float4*)(pA1);
  float4 b0 = *(const float4*)(pB0);
  float4 b1 = *(const float4*)(pB1);

  for (int kt = 0; kt < F_ / BK; ++kt) {
    __syncthreads();  // previous compute done before overwriting LDS
    // write staged regs -> LDS (A transposed)
    As[c4A0 * 4 + 0][rowA0] = a0.x;
    As[c4A0 * 4 + 1][rowA0] = a0.y;
    As[c4A0 * 4 + 2][rowA0] = a0.z;
    As[c4A0 * 4 + 3][rowA0] = a0.w;
    As[c4A1 * 4 + 0][rowA1] = a1.x;
    As[c4A1 * 4 + 1][rowA1] = a1.y;
    As[c4A1 * 4 + 2][rowA1] = a1.z;
    As[c4A1 * 4 + 3][rowA1] = a1.w;
    *(float4*)&Bs[krB0][cB0] = b0;
    *(float4*)&Bs[krB1][cB0] = b1;
    __syncthreads();
    // prefetch next tile into regs (overlaps with compute below)
    if (kt + 1 < F_ / BK) {
      const int k1 = (kt + 1) * BK;
      a0 = *(const float4*)(pA0 + k1);
      a1 = *(const float4*)(pA1 + k1);
      b0 = *(const float4*)(pB0 + (size_t)k1 * C_);
      b1 = *(const float4*)(pB1 + (size_t)k1 * C_);
    }
#pragma unroll
    for (int k = 0; k < BK; ++k) {
      const float4 af0 = *(const float4*)&As[k][ty * 8];
      const float4 af1 = *(const float4*)&As[k][ty * 8 + 4];
      const float4 bf0 = *(const float4*)&Bs[k][tx * 8];
      const float4 bf1 = *(const float4*)&Bs[k][tx * 8 + 4];
      const float av[8] = {af0.x, af0.y, af0.z, af0.w, af1.x, af1.y, af1.z, af1.w};
      const float bv[8] = {bf0.x, bf0.y, bf0.z, bf0.w, bf1.x, bf1.y, bf1.z, bf1.w};
#pragma unroll
      for (int i = 0; i < 8; ++i)
#pragma unroll
        for (int j = 0; j < 8; ++j) acc[i][j] += av[i] * bv[j];
    }
  }

  // epilogue: store 8x8 per thread as float4s
#pragma unroll
  for (int i = 0; i < 8; ++i) {
    const int m = m0 + ty * 8 + i;
    float* op = I + (size_t)m * C_ + n0 + tx * 8;
    *(float4*)op = make_float4(acc[i][0], acc[i][1], acc[i][2], acc[i][3]);
    *(float4*)(op + 4) = make_float4(acc[i][4], acc[i][5], acc[i][6], acc[i][7]);
  }
}

// ---------------------------------------------------------------------------
// Scan: one thread per neuron (b,c); processes CT timesteps of the chunk.
// Exact translation of the JAX step (branches are exclusive on OLD mode).
// ---------------------------------------------------------------------------
__global__ __launch_bounds__(256) void snn_scan_kernel(
    const float* __restrict__ I, float* __restrict__ Vst,
    float* __restrict__ Rst, int* __restrict__ Mst, float* __restrict__ SCst,
    float* __restrict__ out, int CT, int first, int last) {
  const int idx = blockIdx.x * 256 + threadIdx.x;  // b*C_ + c
  float V, refr, sc;
  int mode;
  if (first) {
    V = 0.f; refr = 0.f; sc = 0.f; mode = 0;
  } else {
    V = Vst[idx]; refr = Rst[idx]; mode = Mst[idx]; sc = SCst[idx];
  }
  const int b = idx >> 9;    // / C_
  const int c = idx & 511;   // % C_
  const float* Ip = I + (size_t)b * CT * C_ + c;

  for (int tt = 0; tt < CT; ++tt) {
    const float Iv = Ip[(size_t)tt * C_];
    if (mode == 0) {
      // standard: integrate, leak, floor at STD_POT=0, spike at V_TH=0.4
      V = V + Iv - 0.01f;
      if (V < 0.f) V = 0.f;
      if (V - 0.4f > 0.f) {
        sc += 1.f;
        V = 0.f;      // V_RESET
        refr = 2.f;   // REFRAC
        mode = 1;
      }
    } else if (mode == 1) {
      // absolute refractory: count down
      refr = fmaxf(refr - 1.f, 0.f);
      if (refr <= 0.f) mode = 2;
      if (V < 0.f) V = 0.f;  // REFR_POT clamp
    } else {
      // relative refractory: recover toward standard
      V = V + 0.01f;  // REFR_LEAK
      if (V < 0.f) V = 0.f;
      if (V > 0.f) mode = 0;  // back (STD_POT=0)
    }
  }

  if (last) {
    out[idx] = sc;
  } else {
    Vst[idx] = V; Rst[idx] = refr; Mst[idx] = mode; SCst[idx] = sc;
  }
}

// ---------------------------------------------------------------------------
extern "C" void kernel_launch(void* const* d_in, const int* in_sizes, int n_in,
                              void* d_out, int out_size, void* d_ws,
                              size_t ws_size, hipStream_t stream) {
  const float* X = (const float*)d_in[0];   // [B_, T_, F_]
  const float* Wm = (const float*)d_in[1];  // [F_, C_]
  float* out = (float*)d_out;               // [B_, C_]

  // State buffers: V, refr, sc (float) + mode (int) = 4 * 256KB = 1 MB
  const size_t stbytes = (size_t)4 * B_ * C_ * sizeof(float);

  // Pick largest T-chunk whose I-buffer (+state) fits in d_ws.
  int CT = 256, lct = 8;
  while (CT > 16) {
    const size_t need = (size_t)B_ * CT * C_ * sizeof(float) + stbytes;
    if (need <= ws_size) break;
    CT >>= 1;
    --lct;
  }

  float* Ibuf = (float*)d_ws;
  char* sb = (char*)d_ws + (size_t)B_ * CT * C_ * sizeof(float);
  float* Vst = (float*)sb;
  float* Rst = Vst + B_ * C_;
  float* SCst = Rst + B_ * C_;
  int* Mst = (int*)(SCst + B_ * C_);

  const dim3 ggrid(B_ * CT / BM, C_ / BN);
  for (int t0 = 0; t0 < T_; t0 += CT) {
    snn_gemm_kernel<<<ggrid, 256, 0, stream>>>(X, Wm, Ibuf, t0, CT, lct);
    snn_scan_kernel<<<(B_ * C_) / 256, 256, 0, stream>>>(
        Ibuf, Vst, Rst, Mst, SCst, out, CT, t0 == 0, (t0 + CT) == T_);
  }
}